// Round 3
// baseline (1032.236 us; speedup 1.0000x reference)
//
#include <hip/hip_runtime.h>
#include <hip/hip_bf16.h>
#include <math.h>

// Problem constants (B=4, S=4096 -> T=16384 tokens)
#define TOKENS 16384
#define HD 1024
#define FD 2048
#define NEXP 8
#define MAX_MT 136            // max 256-row m-tiles: floor(32768/256) + 8
#define RP_MAX (MAX_MT * 256) // 34816 padded routed rows

typedef __bf16 bf16x8 __attribute__((ext_vector_type(8)));
typedef float f32x4 __attribute__((ext_vector_type(4)));
typedef unsigned short u16;
typedef unsigned int u32;

__device__ __forceinline__ u16 f2bf(float f) {
    union { float f; u32 u; } v; v.f = f;
    return (u16)((v.u + 0x7FFFu + ((v.u >> 16) & 1u)) >> 16);
}

#define GLOAD16(g, l) __builtin_amdgcn_global_load_lds( \
    (const __attribute__((address_space(1))) u32*)(g),  \
    (__attribute__((address_space(3))) u32*)(l), 16, 0, 0)

// ---------------- routing ----------------

__global__ void init_routing(int* sorted_rid, int* counts, int* fill, int* numTiles) {
    int i = blockIdx.x * blockDim.x + threadIdx.x;
    if (i < RP_MAX) sorted_rid[i] = -1;
    if (i < NEXP) { counts[i] = 0; fill[i] = 0; }
    if (i == 0) *numTiles = 0;
}

__global__ void zero_f32(float4* p, int n4) {
    int i = blockIdx.x * blockDim.x + threadIdx.x;
    if (i < n4) p[i] = make_float4(0.f, 0.f, 0.f, 0.f);
}

__global__ void count_kernel(const int* __restrict__ te, int* counts) {
    int j = blockIdx.x * blockDim.x + threadIdx.x;
    if (j < TOKENS * 2) atomicAdd(&counts[te[j]], 1);
}

__global__ void scan_kernel(const int* __restrict__ counts, int* offs,
                            int* tileE, int* tileRow, int* numTiles) {
    if (blockIdx.x == 0 && threadIdx.x == 0) {
        int o = 0, t = 0;
        for (int e = 0; e < NEXP; e++) {
            offs[e] = o;
            int nt = (counts[e] + 255) >> 8;
            for (int i = 0; i < nt; i++) { tileE[t] = e; tileRow[t] = o + i * 256; t++; }
            o += nt * 256;
        }
        *numTiles = t;
    }
}

__global__ void scatter_kernel(const int* __restrict__ te, const int* __restrict__ offs,
                               int* fill, int* sorted_rid) {
    int j = blockIdx.x * blockDim.x + threadIdx.x;
    if (j < TOKENS * 2) {
        int e = te[j];
        int p = offs[e] + atomicAdd(&fill[e], 1);
        sorted_rid[p] = j;
    }
}

// ---------------- conversions ----------------

__global__ void convert_x(const float* __restrict__ x, u16* __restrict__ xb) {
    int i = blockIdx.x * blockDim.x + threadIdx.x;   // one thread = 8 elems
    const float4* xv = (const float4*)x;
    float4 a = xv[i * 2], b = xv[i * 2 + 1];
    union { u16 s[8]; uint4 v; } o;
    o.s[0] = f2bf(a.x); o.s[1] = f2bf(a.y); o.s[2] = f2bf(a.z); o.s[3] = f2bf(a.w);
    o.s[4] = f2bf(b.x); o.s[5] = f2bf(b.y); o.s[6] = f2bf(b.z); o.s[7] = f2bf(b.w);
    *(uint4*)(xb + (size_t)i * 8) = o.v;
}

// in: [E][K][N] f32  ->  out: [E][N][K] bf16
__global__ void transpose_conv(const float* __restrict__ in, u16* __restrict__ out,
                               int K, int N) {
    __shared__ float tile[32][33];
    int e = blockIdx.z;
    int n0 = blockIdx.x * 32, k0 = blockIdx.y * 32;
    const float* src = in + (size_t)e * K * N;
    u16* dst = out + (size_t)e * N * K;
    int tx = threadIdx.x, ty = threadIdx.y;
    #pragma unroll
    for (int j = 0; j < 32; j += 8)
        tile[ty + j][tx] = src[(size_t)(k0 + ty + j) * N + n0 + tx];
    __syncthreads();
    #pragma unroll
    for (int j = 0; j < 32; j += 8)
        dst[(size_t)(n0 + ty + j) * K + k0 + tx] = f2bf(tile[tx][ty + j]);
}

// ==================================================================
// 256x256 grouped-GEMM core, BK=32, 8 waves (2M x 4N), 4-deep LDS
// ring (4 x 16KB per operand = 128 KiB), counted vmcnt(8), setprio.
//
// LDS tile layout (per operand, per buffer): phys [128 rows][8 x 16B
// slots]. Logical (r, ks) (r 0..255, ks 0..3 of 16B within BK=32):
//   p = r & 127 ; slot' = (r>>7)*4 + ks ; phys slot = slot' ^ (p&7)
// global_load_lds writes linearly: thread tid -> phys row tid>>3,
// slot tid&7 -> inverse-swizzled per-thread GLOBAL source (rule #21).
// ==================================================================

// MFMA phase: 4 m-frags x 4 n-frags
#define MFMA_QUAD(ACCBASE, AFR, BFR)                                            \
    _Pragma("unroll")                                                           \
    for (int mi = 0; mi < 4; mi++)                                              \
        _Pragma("unroll")                                                       \
        for (int nf = 0; nf < 4; nf++)                                          \
            acc[(ACCBASE) + mi][nf] = __builtin_amdgcn_mfma_f32_16x16x32_bf16(  \
                AFR[mi], BFR[nf], acc[(ACCBASE) + mi][nf], 0, 0, 0);

// ---------------- grouped GEMM 1: H_act = gelu(X[gather] @ w1 + b1) ----------------

__global__ __launch_bounds__(512, 2) void gemm1_kernel(
    const u16* __restrict__ Xb, const u16* __restrict__ W1t,
    const float* __restrict__ b1, const int* __restrict__ sorted_rid,
    const int* __restrict__ tileE, const int* __restrict__ tileRow,
    const int* __restrict__ numTiles, u16* __restrict__ Hact)
{
    int mt = blockIdx.y;
    if (mt >= *numTiles) return;
    int e = tileE[mt];
    int row0 = tileRow[mt];
    int n0 = blockIdx.x * 256;

    __shared__ __align__(16) u16 As[4][8192];
    __shared__ __align__(16) u16 Bs[4][8192];
    char* AsB = (char*)&As[0][0];
    char* BsB = (char*)&Bs[0][0];

    const int tid = threadIdx.x;
    const int wave = tid >> 6, lane = tid & 63;
    const int wr = wave >> 2, wc = wave & 3;
    const int laneR = lane & 15, kgrp = lane >> 4;

    // per-thread stage sources (inverse swizzle), advance 32 u16 per K-tile
    const u16* srcA[2]; const u16* srcB[2];
    #pragma unroll
    for (int h = 0; h < 2; h++) {
        int p = h * 64 + (tid >> 3);
        int sl = (tid & 7) ^ (p & 7);
        int r = p + ((sl >> 2) << 7);
        int ks = sl & 3;
        int rid = sorted_rid[row0 + r];
        int tok = rid < 0 ? 0 : (rid >> 1);
        srcA[h] = Xb + (size_t)tok * HD + ks * 8;
        srcB[h] = W1t + ((size_t)e * FD + (n0 + r)) * HD + ks * 8;
    }
    auto stageA = [&](int t_) {
        char* d = AsB + (t_ & 3) * 16384 + wave * 1024;
        GLOAD16(srcA[0] + (size_t)t_ * 32, d);
        GLOAD16(srcA[1] + (size_t)t_ * 32, d + 8192);
    };
    auto stageB = [&](int t_) {
        char* d = BsB + (t_ & 3) * 16384 + wave * 1024;
        GLOAD16(srcB[0] + (size_t)t_ * 32, d);
        GLOAD16(srcB[1] + (size_t)t_ * 32, d + 8192);
    };

    // swizzled LDS read bases
    const int psA = ((wr << 2) | kgrp) ^ (laneR & 7);
    const int psB = (((wc >> 1) << 2) | kgrp) ^ (laneR & 7);
    const char* Ard = AsB + laneR * 128 + psA * 16;
    const char* Brd = BsB + (wc & 1) * 8192 + laneR * 128 + psB * 16;

    f32x4 acc[8][4] = {};
    const int NT = HD / 32;

    // prologue: tiles 0..2 -> bufs 0..2, wait tile 0
    stageA(0); stageB(0); stageA(1); stageB(1); stageA(2); stageB(2);
    asm volatile("s_waitcnt vmcnt(8)" ::: "memory");
    __builtin_amdgcn_s_barrier();

    for (int t = 0; t < NT; t++) {
        const char* Ab = Ard + (t & 3) * 16384;
        const char* Bb = Brd + (t & 3) * 16384;
        // phase 0: B frags + A(mh=0) frags; stage A of t+3
        bf16x8 bfr[4], afr[4];
        #pragma unroll
        for (int nf = 0; nf < 4; nf++) bfr[nf] = *(const bf16x8*)(Bb + nf * 2048);
        #pragma unroll
        for (int mi = 0; mi < 4; mi++) afr[mi] = *(const bf16x8*)(Ab + mi * 2048);
        if (t + 3 < NT) stageA(t + 3);
        __builtin_amdgcn_s_barrier();
        asm volatile("s_waitcnt lgkmcnt(0)" ::: "memory");
        __builtin_amdgcn_sched_barrier(0);
        __builtin_amdgcn_s_setprio(1);
        MFMA_QUAD(0, afr, bfr)
        __builtin_amdgcn_s_setprio(0);
        __builtin_amdgcn_s_barrier();
        // phase 1: A(mh=1) frags; stage B of t+3; boundary counted vmcnt
        bf16x8 afr2[4];
        #pragma unroll
        for (int mi = 0; mi < 4; mi++) afr2[mi] = *(const bf16x8*)(Ab + 8192 + mi * 2048);
        if (t + 3 < NT) stageB(t + 3);
        if (t < NT - 3)       { asm volatile("s_waitcnt vmcnt(8)" ::: "memory"); }
        else if (t == NT - 3) { asm volatile("s_waitcnt vmcnt(4)" ::: "memory"); }
        else if (t == NT - 2) { asm volatile("s_waitcnt vmcnt(0)" ::: "memory"); }
        __builtin_amdgcn_s_barrier();
        asm volatile("s_waitcnt lgkmcnt(0)" ::: "memory");
        __builtin_amdgcn_sched_barrier(0);
        __builtin_amdgcn_s_setprio(1);
        MFMA_QUAD(4, afr2, bfr)
        __builtin_amdgcn_s_setprio(0);
        __builtin_amdgcn_s_barrier();
    }

    // epilogue: bias + exact gelu -> bf16 store
    const float* b1e = b1 + e * FD + n0;
    #pragma unroll
    for (int mf = 0; mf < 8; mf++) {
        int rbase = row0 + wr * 128 + mf * 16 + kgrp * 4;
        #pragma unroll
        for (int nf = 0; nf < 4; nf++) {
            int col = wc * 64 + nf * 16 + laneR;
            float bias = b1e[col];
            #pragma unroll
            for (int r = 0; r < 4; r++) {
                float v = acc[mf][nf][r] + bias;
                v = 0.5f * v * (1.0f + erff(v * 0.70710678118f));
                Hact[(size_t)(rbase + r) * FD + n0 + col] = f2bf(v);
            }
        }
    }
}

// ---------------- grouped GEMM 2: y += fw * (H_act @ w2 + b2) ----------------

__global__ __launch_bounds__(512, 2) void gemm2_kernel(
    const u16* __restrict__ Hact, const u16* __restrict__ W2t,
    const float* __restrict__ b2, const float* __restrict__ ew,
    const int* __restrict__ sorted_rid,
    const int* __restrict__ tileE, const int* __restrict__ tileRow,
    const int* __restrict__ numTiles, float* __restrict__ y)
{
    int mt = blockIdx.y;
    if (mt >= *numTiles) return;
    int e = tileE[mt];
    int row0 = tileRow[mt];
    int n0 = blockIdx.x * 256;

    __shared__ __align__(16) u16 As[4][8192];
    __shared__ __align__(16) u16 Bs[4][8192];
    char* AsB = (char*)&As[0][0];
    char* BsB = (char*)&Bs[0][0];

    const int tid = threadIdx.x;
    const int wave = tid >> 6, lane = tid & 63;
    const int wr = wave >> 2, wc = wave & 3;
    const int laneR = lane & 15, kgrp = lane >> 4;

    const u16* srcA[2]; const u16* srcB[2];
    #pragma unroll
    for (int h = 0; h < 2; h++) {
        int p = h * 64 + (tid >> 3);
        int sl = (tid & 7) ^ (p & 7);
        int r = p + ((sl >> 2) << 7);
        int ks = sl & 3;
        srcA[h] = Hact + (size_t)(row0 + r) * FD + ks * 8;
        srcB[h] = W2t + ((size_t)e * HD + (n0 + r)) * FD + ks * 8;
    }
    auto stageA = [&](int t_) {
        char* d = AsB + (t_ & 3) * 16384 + wave * 1024;
        GLOAD16(srcA[0] + (size_t)t_ * 32, d);
        GLOAD16(srcA[1] + (size_t)t_ * 32, d + 8192);
    };
    auto stageB = [&](int t_) {
        char* d = BsB + (t_ & 3) * 16384 + wave * 1024;
        GLOAD16(srcB[0] + (size_t)t_ * 32, d);
        GLOAD16(srcB[1] + (size_t)t_ * 32, d + 8192);
    };

    const int psA = ((wr << 2) | kgrp) ^ (laneR & 7);
    const int psB = (((wc >> 1) << 2) | kgrp) ^ (laneR & 7);
    const char* Ard = AsB + laneR * 128 + psA * 16;
    const char* Brd = BsB + (wc & 1) * 8192 + laneR * 128 + psB * 16;

    f32x4 acc[8][4] = {};
    const int NT = FD / 32;

    stageA(0); stageB(0); stageA(1); stageB(1); stageA(2); stageB(2);
    asm volatile("s_waitcnt vmcnt(8)" ::: "memory");
    __builtin_amdgcn_s_barrier();

    for (int t = 0; t < NT; t++) {
        const char* Ab = Ard + (t & 3) * 16384;
        const char* Bb = Brd + (t & 3) * 16384;
        bf16x8 bfr[4], afr[4];
        #pragma unroll
        for (int nf = 0; nf < 4; nf++) bfr[nf] = *(const bf16x8*)(Bb + nf * 2048);
        #pragma unroll
        for (int mi = 0; mi < 4; mi++) afr[mi] = *(const bf16x8*)(Ab + mi * 2048);
        if (t + 3 < NT) stageA(t + 3);
        __builtin_amdgcn_s_barrier();
        asm volatile("s_waitcnt lgkmcnt(0)" ::: "memory");
        __builtin_amdgcn_sched_barrier(0);
        __builtin_amdgcn_s_setprio(1);
        MFMA_QUAD(0, afr, bfr)
        __builtin_amdgcn_s_setprio(0);
        __builtin_amdgcn_s_barrier();
        bf16x8 afr2[4];
        #pragma unroll
        for (int mi = 0; mi < 4; mi++) afr2[mi] = *(const bf16x8*)(Ab + 8192 + mi * 2048);
        if (t + 3 < NT) stageB(t + 3);
        if (t < NT - 3)       { asm volatile("s_waitcnt vmcnt(8)" ::: "memory"); }
        else if (t == NT - 3) { asm volatile("s_waitcnt vmcnt(4)" ::: "memory"); }
        else if (t == NT - 2) { asm volatile("s_waitcnt vmcnt(0)" ::: "memory"); }
        __builtin_amdgcn_s_barrier();
        asm volatile("s_waitcnt lgkmcnt(0)" ::: "memory");
        __builtin_amdgcn_sched_barrier(0);
        __builtin_amdgcn_s_setprio(1);
        MFMA_QUAD(4, afr2, bfr)
        __builtin_amdgcn_s_setprio(0);
        __builtin_amdgcn_s_barrier();
    }

    // epilogue: bias, routing weight, atomic scatter-add into y[token]
    const float* b2e = b2 + e * HD + n0;
    #pragma unroll
    for (int mf = 0; mf < 8; mf++) {
        int rbase = row0 + wr * 128 + mf * 16 + kgrp * 4;
        #pragma unroll
        for (int r = 0; r < 4; r++) {
            int rid = sorted_rid[rbase + r];
            if (rid < 0) continue;               // padding row
            float fw = ew[rid];
            float* yrow = y + (size_t)(rid >> 1) * HD + n0;
            #pragma unroll
            for (int nf = 0; nf < 4; nf++) {
                int col = wc * 64 + nf * 16 + laneR;
                atomicAdd(&yrow[col], (acc[mf][nf][r] + b2e[col]) * fw);
            }
        }
    }
}

// ---------------- launch ----------------

extern "C" void kernel_launch(void* const* d_in, const int* in_sizes, int n_in,
                              void* d_out, int out_size, void* d_ws, size_t ws_size,
                              hipStream_t stream) {
    const float* x  = (const float*)d_in[0];
    const float* ew = (const float*)d_in[1];
    const int*   te = (const int*)d_in[2];
    const float* w1 = (const float*)d_in[3];
    const float* b1 = (const float*)d_in[4];
    const float* w2 = (const float*)d_in[5];
    const float* b2 = (const float*)d_in[6];
    float* y = (float*)d_out;

    char* ws = (char*)d_ws;
    u16* Xb   = (u16*)(ws);                      // 33,554,432 B (reused by W2t)
    u16* W2t  = (u16*)(ws);                      //  -- written AFTER gemm1
    u16* W1t  = (u16*)(ws + 33554432);           // 33,554,432 B
    u16* Hact = (u16*)(ws + 67108864);           // 142,606,336 B (34816 x 2048 bf16)
    char* ip  = ws + 209715200;
    int* counts   = (int*)(ip);
    int* fill     = (int*)(ip + 32);
    int* offs     = (int*)(ip + 64);
    int* numTiles = (int*)(ip + 96);
    int* tileE    = (int*)(ip + 128);
    int* tileRow  = (int*)(ip + 128 + 1024);
    int* sorted   = (int*)(ip + 4096);           // RP_MAX ints

    // routing
    init_routing<<<(RP_MAX + 255) / 256, 256, 0, stream>>>(sorted, counts, fill, numTiles);
    zero_f32<<<(out_size / 4 + 255) / 256, 256, 0, stream>>>((float4*)y, out_size / 4);
    count_kernel<<<(TOKENS * 2 + 255) / 256, 256, 0, stream>>>(te, counts);
    scan_kernel<<<1, 64, 0, stream>>>(counts, offs, tileE, tileRow, numTiles);
    scatter_kernel<<<(TOKENS * 2 + 255) / 256, 256, 0, stream>>>(te, offs, fill, sorted);

    // conversions needed by gemm1
    convert_x<<<(TOKENS * HD / 8 + 255) / 256, 256, 0, stream>>>(x, Xb);
    transpose_conv<<<dim3(FD / 32, HD / 32, NEXP), dim3(32, 8), 0, stream>>>(w1, W1t, HD, FD);

    // grouped GEMM 1 (n-tile fast in grid.x so same-mt blocks co-reside)
    gemm1_kernel<<<dim3(FD / 256, MAX_MT), 512, 0, stream>>>(
        Xb, W1t, b1, sorted, tileE, tileRow, numTiles, Hact);

    // w2 transpose AFTER gemm1 (W2t overlays Xb; stream-serialized)
    transpose_conv<<<dim3(HD / 32, FD / 32, NEXP), dim3(32, 8), 0, stream>>>(w2, W2t, FD, HD);

    // grouped GEMM 2
    gemm2_kernel<<<dim3(HD / 256, MAX_MT), 512, 0, stream>>>(
        Hact, W2t, b2, ew, sorted, tileE, tileRow, numTiles, y);
}